// Round 6
// baseline (108.196 us; speedup 1.0000x reference)
//
#include <hip/hip_runtime.h>

#define LOG2E 1.44269504088896340736f

typedef float v2f __attribute__((ext_vector_type(2)));

__device__ __forceinline__ float fexp2(float x){
#if __has_builtin(__builtin_amdgcn_exp2f)
  return __builtin_amdgcn_exp2f(x);
#else
  return exp2f(x);
#endif
}
__device__ __forceinline__ float frcp(float x){
#if __has_builtin(__builtin_amdgcn_rcpf)
  return __builtin_amdgcn_rcpf(x);
#else
  return 1.0f/x;
#endif
}
__device__ __forceinline__ float tanh_fast(float x){
  float e = fexp2(x * (2.0f*LOG2E));
  return 1.0f - 2.0f*frcp(e + 1.0f);
}
__device__ __forceinline__ float4 fma4(float s, float4 w, float4 a){
  a.x = fmaf(s,w.x,a.x); a.y = fmaf(s,w.y,a.y);
  a.z = fmaf(s,w.z,a.z); a.w = fmaf(s,w.w,a.w);
  return a;
}
__device__ __forceinline__ v2f vfma2(v2f a, v2f b, v2f c){
#if __has_builtin(__builtin_elementwise_fma)
  return __builtin_elementwise_fma(a,b,c);
#else
  v2f r; r.x=fmaf(a.x,b.x,c.x); r.y=fmaf(a.y,b.y,c.y); return r;
#endif
}

// Rank-3 attention branch, 4 batches per block.
// S[q,k] = g(q)^T M g(k), M = Aq Ak^T (3x3, scale*log2e folded), g=(x,y,1).
// h = mean_q(Ex/E)*wv0 + mean_q(Ey/E)*wv1 + vb.
// Lane owns rows q=lane, lane+64. LDS layout is SoA in k-PAIRS so the
// k-loop's pk operands are natural register pairs (no in-loop splats):
//   sA[p] = (ux[2p],ux[2p+1], uy[2p],uy[2p+1])
//   sB[p] = (uz[2p],uz[2p+1], xk[2p],xk[2p+1])
//   sYv[k] = y[k]            (read as float4 quads)
// sHbase is the full 80-float block array; this wave writes
// sHbase[hoff .. hoff+DV); the block-wide hbuf store reads sHbase[tix].
template<int DQ, int DV, int NB>
__device__ __forceinline__ void branch_all(
    const float* __restrict__ state, int b0, int n0,
    const float* __restrict__ W, const float* __restrict__ bias,
    float* __restrict__ sA, float* __restrict__ sB, float* __restrict__ sYv,
    float* __restrict__ sHbase, int hoff, float* __restrict__ hbuf,
    int lane, int tix)
{
  const int D = 4*DQ;
  const float qs = LOG2E * (DQ==8 ? 0.35355339059327373f : 0.25f); // log2e/sqrt(dk)

  // M = Aq Ak^T * qs — once per block (batch-independent), uniform operands.
  float M00=0,M01=0,M02=0,M10=0,M11=0,M12=0,M20=0,M21=0,M22=0;
  #pragma unroll
  for (int d=0; d<DQ; ++d) {
    float aq0 = W[d], aq1 = W[D+d], aq2 = bias[d];
    float ak0 = W[DQ+d], ak1 = W[D+DQ+d], ak2 = bias[DQ+d];
    M00 = fmaf(aq0,ak0,M00); M01 = fmaf(aq0,ak1,M01); M02 = fmaf(aq0,ak2,M02);
    M10 = fmaf(aq1,ak0,M10); M11 = fmaf(aq1,ak1,M11); M12 = fmaf(aq1,ak2,M12);
    M20 = fmaf(aq2,ak0,M20); M21 = fmaf(aq2,ak1,M21); M22 = fmaf(aq2,ak2,M22);
  }
  M00*=qs; M01*=qs; M02*=qs; M10*=qs; M11*=qs; M12*=qs; M20*=qs; M21*=qs; M22*=qs;

  float wv0 = 0.f, wv1 = 0.f, vb = 0.f;
  if (lane < DV) { wv0 = W[2*DQ+lane]; wv1 = W[D+2*DQ+lane]; vb = bias[2*DQ+lane]; }

  #pragma unroll 1
  for (int e = 0; e < NB; ++e) {
    const int b = b0 + e;
    const float* sp = state + ((size_t)b*512 + (size_t)(n0 + lane))*3;
    float x0 = sp[0],   y0 = sp[1];
    float x1 = sp[192], y1 = sp[193];

    // SoA pair writes for own k's (k0=lane, k1=lane+64)
    {
      int p = lane >> 1, h = lane & 1;
      float ux = fmaf(M00,x0, fmaf(M01,y0, M02));
      float uy = fmaf(M10,x0, fmaf(M11,y0, M12));
      float uz = fmaf(M20,x0, fmaf(M21,y0, M22));
      sA[p*4 + h]     = ux;  sA[p*4 + 2 + h] = uy;
      sB[p*4 + h]     = uz;  sB[p*4 + 2 + h] = x0;
      sYv[lane]       = y0;
      int p1 = p + 32;
      float vx = fmaf(M00,x1, fmaf(M01,y1, M02));
      float vy = fmaf(M10,x1, fmaf(M11,y1, M12));
      float vz = fmaf(M20,x1, fmaf(M21,y1, M22));
      sA[p1*4 + h]     = vx;  sA[p1*4 + 2 + h] = vy;
      sB[p1*4 + h]     = vz;  sB[p1*4 + 2 + h] = x1;
      sYv[lane + 64]   = y1;
    }
    __syncthreads();

    v2f X0; X0.x=x0; X0.y=x0;  v2f Y0; Y0.x=y0; Y0.y=y0;
    v2f X1; X1.x=x1; X1.y=x1;  v2f Y1; Y1.x=y1; Y1.y=y1;
    v2f E0={0.f,0.f}, Ex0={0.f,0.f}, Ey0={0.f,0.f};
    v2f E1={0.f,0.f}, Ex1={0.f,0.f}, Ey1={0.f,0.f};
    const float4* A4 = (const float4*)sA;
    const float4* B4 = (const float4*)sB;
    const float4* Y4 = (const float4*)sYv;
    #pragma unroll 2
    for (int pp = 0; pp < 32; ++pp) {     // 2 k-pairs (4 k) per iter
      float4 Av0 = A4[2*pp], Av1 = A4[2*pp+1];
      float4 Bv0 = B4[2*pp], Bv1 = B4[2*pp+1];
      float4 Yq  = Y4[pp];
      {
        v2f ux; ux.x=Av0.x; ux.y=Av0.y;  v2f uy; uy.x=Av0.z; uy.y=Av0.w;
        v2f uz; uz.x=Bv0.x; uz.y=Bv0.y;  v2f xk; xk.x=Bv0.z; xk.y=Bv0.w;
        v2f yk; yk.x=Yq.x;  yk.y=Yq.y;
        v2f s0 = vfma2(X0, ux, vfma2(Y0, uy, uz));
        v2f s1 = vfma2(X1, ux, vfma2(Y1, uy, uz));
        v2f e0, e1;
        e0.x = fexp2(s0.x); e0.y = fexp2(s0.y);
        e1.x = fexp2(s1.x); e1.y = fexp2(s1.y);
        E0 += e0; Ex0 = vfma2(e0, xk, Ex0); Ey0 = vfma2(e0, yk, Ey0);
        E1 += e1; Ex1 = vfma2(e1, xk, Ex1); Ey1 = vfma2(e1, yk, Ey1);
      }
      {
        v2f ux; ux.x=Av1.x; ux.y=Av1.y;  v2f uy; uy.x=Av1.z; uy.y=Av1.w;
        v2f uz; uz.x=Bv1.x; uz.y=Bv1.y;  v2f xk; xk.x=Bv1.z; xk.y=Bv1.w;
        v2f yk; yk.x=Yq.z;  yk.y=Yq.w;
        v2f s0 = vfma2(X0, ux, vfma2(Y0, uy, uz));
        v2f s1 = vfma2(X1, ux, vfma2(Y1, uy, uz));
        v2f e0, e1;
        e0.x = fexp2(s0.x); e0.y = fexp2(s0.y);
        e1.x = fexp2(s1.x); e1.y = fexp2(s1.y);
        E0 += e0; Ex0 = vfma2(e0, xk, Ex0); Ey0 = vfma2(e0, yk, Ey0);
        E1 += e1; Ex1 = vfma2(e1, xk, Ex1); Ey1 = vfma2(e1, yk, Ey1);
      }
    }
    float r0 = frcp(E0.x + E0.y), r1 = frcp(E1.x + E1.y);
    float gx = fmaf(Ex0.x + Ex0.y, r0, (Ex1.x + Ex1.y) * r1);
    float gy = fmaf(Ey0.x + Ey0.y, r0, (Ey1.x + Ey1.y) * r1);
    #pragma unroll
    for (int m=1; m<64; m<<=1) {
      gx += __shfl_xor(gx, m, 64);
      gy += __shfl_xor(gy, m, 64);
    }
    gx *= 0.0078125f;  // mean over 128 rows
    gy *= 0.0078125f;
    if (lane < DV) sHbase[hoff + lane] = fmaf(gx, wv0, fmaf(gy, wv1, vb));
    __syncthreads();
    if (tix < 80) hbuf[(size_t)b*80 + tix] = sHbase[tix];   // BASE pointer!
  }
}

__global__ __launch_bounds__(256)
void attn_kernel(const float* __restrict__ state,
    const float* __restrict__ W_RT, const float* __restrict__ b_RT,
    const float* __restrict__ W_OB, const float* __restrict__ b_OB,
    const float* __restrict__ W_RS, const float* __restrict__ b_RS,
    const float* __restrict__ W_TG, const float* __restrict__ b_TG,
    float* __restrict__ hbuf)
{
  __shared__ float sA[4][256] __attribute__((aligned(16)));
  __shared__ float sB[4][256] __attribute__((aligned(16)));
  __shared__ float sY[4][128] __attribute__((aligned(16)));
  __shared__ float sH[80];
  const int b0   = blockIdx.x * 4;
  const int wave = threadIdx.x >> 6;
  const int lane = threadIdx.x & 63;

  const float* W;  const float* bb;
  if      (wave == 0) { W = W_RT; bb = b_RT; }
  else if (wave == 1) { W = W_OB; bb = b_OB; }
  else if (wave == 2) { W = W_RS; bb = b_RS; }
  else                { W = W_TG; bb = b_TG; }
  const int n0 = wave * 128;
  const int hoff = wave * 16;   // RT:0 OB:16 RS:32 TG:48..79

  if (wave < 3)
    branch_all<8 ,16,4>(state, b0, n0, W, bb, sA[wave], sB[wave], sY[wave],
                        sH, hoff, hbuf, lane, threadIdx.x);
  else
    branch_all<16,32,4>(state, b0, n0, W, bb, sA[wave], sB[wave], sY[wave],
                        sH, hoff, hbuf, lane, threadIdx.x);
}

// MLP: 80 -> 256 (tanh) -> 256 (tanh) -> 1. 8 batch rows per block,
// grid 512 = exactly 2 blocks/CU. Thread t: unit-quad q=t>>2 (float4
// coalesced weight loads), row-group rg=t&3 (rows 2rg,2rg+1).
// Weight loads register-pipelined depth 4 (L1) / depth 8 (L2) to cover
// L2 latency at 2 waves/SIMD.
__global__ __launch_bounds__(256, 2)
void mlp_kernel(const float* __restrict__ hbuf,
    const float* __restrict__ W1, const float* __restrict__ b1,
    const float* __restrict__ W2, const float* __restrict__ b2,
    const float* __restrict__ W3, const float* __restrict__ b3,
    float* __restrict__ out)
{
  __shared__ float sHin[8][84];
  __shared__ float sH1[8][260];
  __shared__ float sRed[4][8];
  const int t  = threadIdx.x;
  const int b0 = blockIdx.x * 8;
  const int q  = t >> 2;
  const int rg = t & 3;
  const int r0 = 2*rg, r1 = r0 + 1;
  const int wave = t >> 6;

  for (int i = t; i < 8*80; i += 256) sHin[i/80][i%80] = hbuf[(size_t)b0*80 + i];
  __syncthreads();

  const float4* W1v = (const float4*)W1;   // [row][64] float4s
  const float4* W2v = (const float4*)W2;

  // ---- layer 1: 80 -> 256, tanh (depth-4 pipeline) ----
  float4 acc0 = ((const float4*)b1)[q];
  float4 acc1 = acc0;
  {
    float4 wb[4][4];
    #pragma unroll
    for (int p=0; p<4; ++p)
      #pragma unroll
      for (int jj=0; jj<4; ++jj) wb[p][jj] = W1v[(size_t)(4*p+jj)*64 + q];
    #pragma unroll 4
    for (int i4 = 0; i4 < 16; ++i4) {
      float4 h0 = *(const float4*)&sHin[r0][i4*4];
      float4 h1 = *(const float4*)&sHin[r1][i4*4];
      float4 w0=wb[i4&3][0], w1=wb[i4&3][1], w2=wb[i4&3][2], w3=wb[i4&3][3];
      #pragma unroll
      for (int jj=0; jj<4; ++jj) wb[i4&3][jj] = W1v[(size_t)((i4+4)*4+jj)*64 + q];
      acc0 = fma4(h0.x,w0, fma4(h0.y,w1, fma4(h0.z,w2, fma4(h0.w,w3, acc0))));
      acc1 = fma4(h1.x,w0, fma4(h1.y,w1, fma4(h1.z,w2, fma4(h1.w,w3, acc1))));
    }
    #pragma unroll
    for (int i4 = 16; i4 < 20; ++i4) {
      float4 h0 = *(const float4*)&sHin[r0][i4*4];
      float4 h1 = *(const float4*)&sHin[r1][i4*4];
      float4 w0=wb[i4&3][0], w1=wb[i4&3][1], w2=wb[i4&3][2], w3=wb[i4&3][3];
      acc0 = fma4(h0.x,w0, fma4(h0.y,w1, fma4(h0.z,w2, fma4(h0.w,w3, acc0))));
      acc1 = fma4(h1.x,w0, fma4(h1.y,w1, fma4(h1.z,w2, fma4(h1.w,w3, acc1))));
    }
  }
  {
    float4 o0, o1;
    o0.x=tanh_fast(acc0.x); o0.y=tanh_fast(acc0.y); o0.z=tanh_fast(acc0.z); o0.w=tanh_fast(acc0.w);
    o1.x=tanh_fast(acc1.x); o1.y=tanh_fast(acc1.y); o1.z=tanh_fast(acc1.z); o1.w=tanh_fast(acc1.w);
    *(float4*)&sH1[r0][4*q] = o0;
    *(float4*)&sH1[r1][4*q] = o1;
  }
  __syncthreads();

  // ---- layer 2: 256 -> 256, tanh (depth-8 pipeline) ----
  float4 acc2_0 = ((const float4*)b2)[q];
  float4 acc2_1 = acc2_0;
  {
    float4 wb[8][4];
    #pragma unroll
    for (int p=0; p<8; ++p)
      #pragma unroll
      for (int jj=0; jj<4; ++jj) wb[p][jj] = W2v[(size_t)(4*p+jj)*64 + q];
    #pragma unroll 8
    for (int i4 = 0; i4 < 56; ++i4) {
      float4 h0 = *(const float4*)&sH1[r0][i4*4];
      float4 h1 = *(const float4*)&sH1[r1][i4*4];
      float4 w0=wb[i4&7][0], w1=wb[i4&7][1], w2=wb[i4&7][2], w3=wb[i4&7][3];
      #pragma unroll
      for (int jj=0; jj<4; ++jj) wb[i4&7][jj] = W2v[(size_t)((i4+8)*4+jj)*64 + q];
      acc2_0 = fma4(h0.x,w0, fma4(h0.y,w1, fma4(h0.z,w2, fma4(h0.w,w3, acc2_0))));
      acc2_1 = fma4(h1.x,w0, fma4(h1.y,w1, fma4(h1.z,w2, fma4(h1.w,w3, acc2_1))));
    }
    #pragma unroll
    for (int i4 = 56; i4 < 64; ++i4) {
      float4 h0 = *(const float4*)&sH1[r0][i4*4];
      float4 h1 = *(const float4*)&sH1[r1][i4*4];
      float4 w0=wb[i4&7][0], w1=wb[i4&7][1], w2=wb[i4&7][2], w3=wb[i4&7][3];
      acc2_0 = fma4(h0.x,w0, fma4(h0.y,w1, fma4(h0.z,w2, fma4(h0.w,w3, acc2_0))));
      acc2_1 = fma4(h1.x,w0, fma4(h1.y,w1, fma4(h1.z,w2, fma4(h1.w,w3, acc2_1))));
    }
  }

  // ---- layer 3: 256 -> 1 ----
  float4 w3v = ((const float4*)W3)[q];
  float p0 = tanh_fast(acc2_0.x)*w3v.x + tanh_fast(acc2_0.y)*w3v.y
           + tanh_fast(acc2_0.z)*w3v.z + tanh_fast(acc2_0.w)*w3v.w;
  float p1 = tanh_fast(acc2_1.x)*w3v.x + tanh_fast(acc2_1.y)*w3v.y
           + tanh_fast(acc2_1.z)*w3v.z + tanh_fast(acc2_1.w)*w3v.w;
  #pragma unroll
  for (int m=4; m<64; m<<=1) {
    p0 += __shfl_xor(p0, m, 64);
    p1 += __shfl_xor(p1, m, 64);
  }
  if ((t & 63) == rg) { sRed[wave][r0] = p0; sRed[wave][r1] = p1; }
  __syncthreads();
  if (t < 8)
    out[b0 + t] = sRed[0][t] + sRed[1][t] + sRed[2][t] + sRed[3][t] + b3[0];
}

extern "C" void kernel_launch(void* const* d_in, const int* in_sizes, int n_in,
                              void* d_out, int out_size, void* d_ws, size_t ws_size,
                              hipStream_t stream) {
  const float* state = (const float*)d_in[0];
  const float* W_RT = (const float*)d_in[5];
  const float* b_RT = (const float*)d_in[6];
  const float* W_OB = (const float*)d_in[7];
  const float* b_OB = (const float*)d_in[8];
  const float* W_RS = (const float*)d_in[9];
  const float* b_RS = (const float*)d_in[10];
  const float* W_TG = (const float*)d_in[11];
  const float* b_TG = (const float*)d_in[12];
  const float* W1 = (const float*)d_in[13];
  const float* b1 = (const float*)d_in[14];
  const float* W2 = (const float*)d_in[15];
  const float* b2 = (const float*)d_in[16];
  const float* W3 = (const float*)d_in[17];
  const float* b3 = (const float*)d_in[18];

  float* hbuf = (float*)d_ws;   // 4096 x 80 f32 = 1.31 MB

  attn_kernel<<<1024, 256, 0, stream>>>(state,
      W_RT, b_RT, W_OB, b_OB, W_RS, b_RS, W_TG, b_TG, hbuf);
  mlp_kernel<<<512, 256, 0, stream>>>(hbuf, W1, b1, W2, b2, W3, b3,
      (float*)d_out);
}

// Round 7
// 65.139 us; speedup vs baseline: 1.6610x; 1.6610x over previous
//
#include <hip/hip_runtime.h>

#define LOG2E 1.44269504088896340736f

typedef float v2f __attribute__((ext_vector_type(2)));

__device__ __forceinline__ float fexp2(float x){
#if __has_builtin(__builtin_amdgcn_exp2f)
  return __builtin_amdgcn_exp2f(x);
#else
  return exp2f(x);
#endif
}
__device__ __forceinline__ float frcp(float x){
#if __has_builtin(__builtin_amdgcn_rcpf)
  return __builtin_amdgcn_rcpf(x);
#else
  return 1.0f/x;
#endif
}
__device__ __forceinline__ float tanh_fast(float x){
  float e = fexp2(x * (2.0f*LOG2E));
  return 1.0f - 2.0f*frcp(e + 1.0f);
}
__device__ __forceinline__ float4 fma4(float s, float4 w, float4 a){
  a.x = fmaf(s,w.x,a.x); a.y = fmaf(s,w.y,a.y);
  a.z = fmaf(s,w.z,a.z); a.w = fmaf(s,w.w,a.w);
  return a;
}
__device__ __forceinline__ v2f vfma2(v2f a, v2f b, v2f c){
#if __has_builtin(__builtin_elementwise_fma)
  return __builtin_elementwise_fma(a,b,c);
#else
  v2f r; r.x=fmaf(a.x,b.x,c.x); r.y=fmaf(a.y,b.y,c.y); return r;
#endif
}

// Rank-3 attention branch, 4 batches per block. (unchanged from R5 — passed)
// S[q,k] = g(q)^T M g(k), M = Aq Ak^T (3x3, scale*log2e folded), g=(x,y,1).
// h = mean_q(Ex/E)*wv0 + mean_q(Ey/E)*wv1 + vb.
// Lane owns rows q=lane, lane+64. LDS layout is SoA in k-PAIRS so the
// k-loop's pk operands are natural register pairs (no in-loop splats).
template<int DQ, int DV, int NB>
__device__ __forceinline__ void branch_all(
    const float* __restrict__ state, int b0, int n0,
    const float* __restrict__ W, const float* __restrict__ bias,
    float* __restrict__ sA, float* __restrict__ sB, float* __restrict__ sYv,
    float* __restrict__ sHbase, int hoff, float* __restrict__ hbuf,
    int lane, int tix)
{
  const int D = 4*DQ;
  const float qs = LOG2E * (DQ==8 ? 0.35355339059327373f : 0.25f); // log2e/sqrt(dk)

  // M = Aq Ak^T * qs — once per block (batch-independent), uniform operands.
  float M00=0,M01=0,M02=0,M10=0,M11=0,M12=0,M20=0,M21=0,M22=0;
  #pragma unroll
  for (int d=0; d<DQ; ++d) {
    float aq0 = W[d], aq1 = W[D+d], aq2 = bias[d];
    float ak0 = W[DQ+d], ak1 = W[D+DQ+d], ak2 = bias[DQ+d];
    M00 = fmaf(aq0,ak0,M00); M01 = fmaf(aq0,ak1,M01); M02 = fmaf(aq0,ak2,M02);
    M10 = fmaf(aq1,ak0,M10); M11 = fmaf(aq1,ak1,M11); M12 = fmaf(aq1,ak2,M12);
    M20 = fmaf(aq2,ak0,M20); M21 = fmaf(aq2,ak1,M21); M22 = fmaf(aq2,ak2,M22);
  }
  M00*=qs; M01*=qs; M02*=qs; M10*=qs; M11*=qs; M12*=qs; M20*=qs; M21*=qs; M22*=qs;

  float wv0 = 0.f, wv1 = 0.f, vb = 0.f;
  if (lane < DV) { wv0 = W[2*DQ+lane]; wv1 = W[D+2*DQ+lane]; vb = bias[2*DQ+lane]; }

  #pragma unroll 1
  for (int e = 0; e < NB; ++e) {
    const int b = b0 + e;
    const float* sp = state + ((size_t)b*512 + (size_t)(n0 + lane))*3;
    float x0 = sp[0],   y0 = sp[1];
    float x1 = sp[192], y1 = sp[193];

    // SoA pair writes for own k's (k0=lane, k1=lane+64)
    {
      int p = lane >> 1, h = lane & 1;
      float ux = fmaf(M00,x0, fmaf(M01,y0, M02));
      float uy = fmaf(M10,x0, fmaf(M11,y0, M12));
      float uz = fmaf(M20,x0, fmaf(M21,y0, M22));
      sA[p*4 + h]     = ux;  sA[p*4 + 2 + h] = uy;
      sB[p*4 + h]     = uz;  sB[p*4 + 2 + h] = x0;
      sYv[lane]       = y0;
      int p1 = p + 32;
      float vx = fmaf(M00,x1, fmaf(M01,y1, M02));
      float vy = fmaf(M10,x1, fmaf(M11,y1, M12));
      float vz = fmaf(M20,x1, fmaf(M21,y1, M22));
      sA[p1*4 + h]     = vx;  sA[p1*4 + 2 + h] = vy;
      sB[p1*4 + h]     = vz;  sB[p1*4 + 2 + h] = x1;
      sYv[lane + 64]   = y1;
    }
    __syncthreads();

    v2f X0; X0.x=x0; X0.y=x0;  v2f Y0; Y0.x=y0; Y0.y=y0;
    v2f X1; X1.x=x1; X1.y=x1;  v2f Y1; Y1.x=y1; Y1.y=y1;
    v2f E0={0.f,0.f}, Ex0={0.f,0.f}, Ey0={0.f,0.f};
    v2f E1={0.f,0.f}, Ex1={0.f,0.f}, Ey1={0.f,0.f};
    const float4* A4 = (const float4*)sA;
    const float4* B4 = (const float4*)sB;
    const float4* Y4 = (const float4*)sYv;
    #pragma unroll 2
    for (int pp = 0; pp < 32; ++pp) {     // 2 k-pairs (4 k) per iter
      float4 Av0 = A4[2*pp], Av1 = A4[2*pp+1];
      float4 Bv0 = B4[2*pp], Bv1 = B4[2*pp+1];
      float4 Yq  = Y4[pp];
      {
        v2f ux; ux.x=Av0.x; ux.y=Av0.y;  v2f uy; uy.x=Av0.z; uy.y=Av0.w;
        v2f uz; uz.x=Bv0.x; uz.y=Bv0.y;  v2f xk; xk.x=Bv0.z; xk.y=Bv0.w;
        v2f yk; yk.x=Yq.x;  yk.y=Yq.y;
        v2f s0 = vfma2(X0, ux, vfma2(Y0, uy, uz));
        v2f s1 = vfma2(X1, ux, vfma2(Y1, uy, uz));
        v2f e0, e1;
        e0.x = fexp2(s0.x); e0.y = fexp2(s0.y);
        e1.x = fexp2(s1.x); e1.y = fexp2(s1.y);
        E0 += e0; Ex0 = vfma2(e0, xk, Ex0); Ey0 = vfma2(e0, yk, Ey0);
        E1 += e1; Ex1 = vfma2(e1, xk, Ex1); Ey1 = vfma2(e1, yk, Ey1);
      }
      {
        v2f ux; ux.x=Av1.x; ux.y=Av1.y;  v2f uy; uy.x=Av1.z; uy.y=Av1.w;
        v2f uz; uz.x=Bv1.x; uz.y=Bv1.y;  v2f xk; xk.x=Bv1.z; xk.y=Bv1.w;
        v2f yk; yk.x=Yq.z;  yk.y=Yq.w;
        v2f s0 = vfma2(X0, ux, vfma2(Y0, uy, uz));
        v2f s1 = vfma2(X1, ux, vfma2(Y1, uy, uz));
        v2f e0, e1;
        e0.x = fexp2(s0.x); e0.y = fexp2(s0.y);
        e1.x = fexp2(s1.x); e1.y = fexp2(s1.y);
        E0 += e0; Ex0 = vfma2(e0, xk, Ex0); Ey0 = vfma2(e0, yk, Ey0);
        E1 += e1; Ex1 = vfma2(e1, xk, Ex1); Ey1 = vfma2(e1, yk, Ey1);
      }
    }
    float r0 = frcp(E0.x + E0.y), r1 = frcp(E1.x + E1.y);
    float gx = fmaf(Ex0.x + Ex0.y, r0, (Ex1.x + Ex1.y) * r1);
    float gy = fmaf(Ey0.x + Ey0.y, r0, (Ey1.x + Ey1.y) * r1);
    #pragma unroll
    for (int m=1; m<64; m<<=1) {
      gx += __shfl_xor(gx, m, 64);
      gy += __shfl_xor(gy, m, 64);
    }
    gx *= 0.0078125f;  // mean over 128 rows
    gy *= 0.0078125f;
    if (lane < DV) sHbase[hoff + lane] = fmaf(gx, wv0, fmaf(gy, wv1, vb));
    __syncthreads();
    if (tix < 80) hbuf[(size_t)b*80 + tix] = sHbase[tix];   // BASE pointer!
  }
}

__global__ __launch_bounds__(256)
void attn_kernel(const float* __restrict__ state,
    const float* __restrict__ W_RT, const float* __restrict__ b_RT,
    const float* __restrict__ W_OB, const float* __restrict__ b_OB,
    const float* __restrict__ W_RS, const float* __restrict__ b_RS,
    const float* __restrict__ W_TG, const float* __restrict__ b_TG,
    float* __restrict__ hbuf)
{
  __shared__ float sA[4][256] __attribute__((aligned(16)));
  __shared__ float sB[4][256] __attribute__((aligned(16)));
  __shared__ float sY[4][128] __attribute__((aligned(16)));
  __shared__ float sH[80];
  const int b0   = blockIdx.x * 4;
  const int wave = threadIdx.x >> 6;
  const int lane = threadIdx.x & 63;

  const float* W;  const float* bb;
  if      (wave == 0) { W = W_RT; bb = b_RT; }
  else if (wave == 1) { W = W_OB; bb = b_OB; }
  else if (wave == 2) { W = W_RS; bb = b_RS; }
  else                { W = W_TG; bb = b_TG; }
  const int n0 = wave * 128;
  const int hoff = wave * 16;   // RT:0 OB:16 RS:32 TG:48..79

  if (wave < 3)
    branch_all<8 ,16,4>(state, b0, n0, W, bb, sA[wave], sB[wave], sY[wave],
                        sH, hoff, hbuf, lane, threadIdx.x);
  else
    branch_all<16,32,4>(state, b0, n0, W, bb, sA[wave], sB[wave], sY[wave],
                        sH, hoff, hbuf, lane, threadIdx.x);
}

// MLP: 80 -> 256 (tanh) -> 256 (tanh) -> 1.
// 16 batch rows per block, grid 256 = exactly 1 block/CU (no tail).
// Thread t: unit-quad q=t>>2 (units 4q..4q+3, float4 coalesced weight
// loads), row-group rg=t&3 (rows 4rg..4rg+3). 16 fma4 (=64 v_fma, ~128 cyc)
// per 4 weight loads -> depth-4 register prefetch (static i4&3 indexing
// under full unroll) covers ~300cyc L2 latency. launch_bounds(256,1)
// lifts the VGPR cap so the wb[4][4] pipeline (64 VGPR) never spills.
__global__ __launch_bounds__(256, 1)
void mlp_kernel(const float* __restrict__ hbuf,
    const float* __restrict__ W1, const float* __restrict__ b1,
    const float* __restrict__ W2, const float* __restrict__ b2,
    const float* __restrict__ W3, const float* __restrict__ b3,
    float* __restrict__ out)
{
  __shared__ float sHin[16][84];   // 84*4B = 336B row pitch (16B-aligned)
  __shared__ float sH1[16][260];   // 260*4B = 1040B row pitch (16B-aligned)
  __shared__ float sRed[4][16];
  const int t  = threadIdx.x;
  const int b0 = blockIdx.x * 16;
  const int q  = t >> 2;   // unit quad 0..63
  const int rg = t & 3;    // rows 4rg .. 4rg+3
  const int wave = t >> 6;

  for (int i = t; i < 16*80; i += 256) sHin[i/80][i%80] = hbuf[(size_t)b0*80 + i];
  __syncthreads();

  const float4* W1v = (const float4*)W1;   // [row][64] float4s
  const float4* W2v = (const float4*)W2;

  // ---- layer 1: 80 -> 256, tanh (depth-4 pipeline) ----
  float4 acc[4];
  {
    float4 bq = ((const float4*)b1)[q];
    acc[0]=bq; acc[1]=bq; acc[2]=bq; acc[3]=bq;
    float4 wb[4][4];
    #pragma unroll
    for (int p=0; p<4; ++p)
      #pragma unroll
      for (int jj=0; jj<4; ++jj) wb[p][jj] = W1v[(size_t)(4*p+jj)*64 + q];
    #pragma unroll 4
    for (int i4 = 0; i4 < 16; ++i4) {
      float4 w0=wb[i4&3][0], w1=wb[i4&3][1], w2=wb[i4&3][2], w3=wb[i4&3][3];
      #pragma unroll
      for (int jj=0; jj<4; ++jj) wb[i4&3][jj] = W1v[(size_t)((i4+4)*4+jj)*64 + q];
      #pragma unroll
      for (int r=0; r<4; ++r) {
        float4 h = *(const float4*)&sHin[4*rg+r][i4*4];
        acc[r] = fma4(h.x,w0, fma4(h.y,w1, fma4(h.z,w2, fma4(h.w,w3, acc[r]))));
      }
    }
    #pragma unroll
    for (int i4 = 16; i4 < 20; ++i4) {
      float4 w0=wb[i4&3][0], w1=wb[i4&3][1], w2=wb[i4&3][2], w3=wb[i4&3][3];
      #pragma unroll
      for (int r=0; r<4; ++r) {
        float4 h = *(const float4*)&sHin[4*rg+r][i4*4];
        acc[r] = fma4(h.x,w0, fma4(h.y,w1, fma4(h.z,w2, fma4(h.w,w3, acc[r]))));
      }
    }
  }
  #pragma unroll
  for (int r=0; r<4; ++r) {
    float4 o;
    o.x=tanh_fast(acc[r].x); o.y=tanh_fast(acc[r].y);
    o.z=tanh_fast(acc[r].z); o.w=tanh_fast(acc[r].w);
    *(float4*)&sH1[4*rg+r][4*q] = o;
  }
  __syncthreads();

  // ---- layer 2: 256 -> 256, tanh (depth-4 pipeline) ----
  float4 acc2[4];
  {
    float4 bq = ((const float4*)b2)[q];
    acc2[0]=bq; acc2[1]=bq; acc2[2]=bq; acc2[3]=bq;
    float4 wb[4][4];
    #pragma unroll
    for (int p=0; p<4; ++p)
      #pragma unroll
      for (int jj=0; jj<4; ++jj) wb[p][jj] = W2v[(size_t)(4*p+jj)*64 + q];
    #pragma unroll 4
    for (int i4 = 0; i4 < 60; ++i4) {
      float4 w0=wb[i4&3][0], w1=wb[i4&3][1], w2=wb[i4&3][2], w3=wb[i4&3][3];
      #pragma unroll
      for (int jj=0; jj<4; ++jj) wb[i4&3][jj] = W2v[(size_t)((i4+4)*4+jj)*64 + q];
      #pragma unroll
      for (int r=0; r<4; ++r) {
        float4 h = *(const float4*)&sH1[4*rg+r][i4*4];
        acc2[r] = fma4(h.x,w0, fma4(h.y,w1, fma4(h.z,w2, fma4(h.w,w3, acc2[r]))));
      }
    }
    #pragma unroll
    for (int i4 = 60; i4 < 64; ++i4) {
      float4 w0=wb[i4&3][0], w1=wb[i4&3][1], w2=wb[i4&3][2], w3=wb[i4&3][3];
      #pragma unroll
      for (int r=0; r<4; ++r) {
        float4 h = *(const float4*)&sH1[4*rg+r][i4*4];
        acc2[r] = fma4(h.x,w0, fma4(h.y,w1, fma4(h.z,w2, fma4(h.w,w3, acc2[r]))));
      }
    }
  }

  // ---- layer 3: 256 -> 1 ----
  float4 w3v = ((const float4*)W3)[q];
  float p[4];
  #pragma unroll
  for (int r=0; r<4; ++r) {
    p[r] = tanh_fast(acc2[r].x)*w3v.x + tanh_fast(acc2[r].y)*w3v.y
         + tanh_fast(acc2[r].z)*w3v.z + tanh_fast(acc2[r].w)*w3v.w;
  }
  #pragma unroll
  for (int m=4; m<64; m<<=1) {   // reduce over the 16 unit-quads in this wave
    #pragma unroll
    for (int r=0; r<4; ++r) p[r] += __shfl_xor(p[r], m, 64);
  }
  if ((t & 63) == rg) {          // lane rg holds rows 4rg..4rg+3
    #pragma unroll
    for (int r=0; r<4; ++r) sRed[wave][4*rg + r] = p[r];
  }
  __syncthreads();
  if (t < 16)
    out[b0 + t] = sRed[0][t] + sRed[1][t] + sRed[2][t] + sRed[3][t] + b3[0];
}

extern "C" void kernel_launch(void* const* d_in, const int* in_sizes, int n_in,
                              void* d_out, int out_size, void* d_ws, size_t ws_size,
                              hipStream_t stream) {
  const float* state = (const float*)d_in[0];
  const float* W_RT = (const float*)d_in[5];
  const float* b_RT = (const float*)d_in[6];
  const float* W_OB = (const float*)d_in[7];
  const float* b_OB = (const float*)d_in[8];
  const float* W_RS = (const float*)d_in[9];
  const float* b_RS = (const float*)d_in[10];
  const float* W_TG = (const float*)d_in[11];
  const float* b_TG = (const float*)d_in[12];
  const float* W1 = (const float*)d_in[13];
  const float* b1 = (const float*)d_in[14];
  const float* W2 = (const float*)d_in[15];
  const float* b2 = (const float*)d_in[16];
  const float* W3 = (const float*)d_in[17];
  const float* b3 = (const float*)d_in[18];

  float* hbuf = (float*)d_ws;   // 4096 x 80 f32 = 1.31 MB

  attn_kernel<<<1024, 256, 0, stream>>>(state,
      W_RT, b_RT, W_OB, b_OB, W_RS, b_RS, W_TG, b_TG, hbuf);
  mlp_kernel<<<256, 256, 0, stream>>>(hbuf, W1, b1, W2, b2, W3, b3,
      (float*)d_out);
}